// Round 1
// baseline (204.586 us; speedup 1.0000x reference)
//
#include <hip/hip_runtime.h>

// Problem constants (B=8, T_dec=64, T_enc=512, H2=512)
namespace {
constexpr int kH  = 512;
constexpr int kTD = 64;
constexpr int kTE = 512;
constexpr int kB  = 8;
constexpr int kRD = kB * kTD;   // 512 decoder rows
constexpr int kRE = kB * kTE;   // 4096 encoder rows
}

// ---------------------------------------------------------------------------
// C[M,N] = A[M,K] @ B[N,K]^T   (both K-contiguous).  64x64 tile, 256 threads,
// 4x4 micro-tile per thread. M,N,K multiples of 64/16 (true for this problem).
// ---------------------------------------------------------------------------
__global__ __launch_bounds__(256) void gemm_nt(
    const float* __restrict__ A, int lda,
    const float* __restrict__ B, int ldb,
    float* __restrict__ C, int ldc, int K)
{
    __shared__ __align__(16) float As[16][68];
    __shared__ __align__(16) float Bs[16][68];
    const int t  = threadIdx.x;
    const int tx = t & 15, ty = t >> 4;
    const int rb = blockIdx.y * 64, cb = blockIdx.x * 64;
    const int lr = t >> 2;          // row (0..63) this thread stages
    const int lq = (t & 3) << 2;    // k-quad offset
    float acc[4][4] = {};

    for (int k0 = 0; k0 < K; k0 += 16) {
        const float4 av = *(const float4*)(A + (size_t)(rb + lr) * lda + k0 + lq);
        const float4 bv = *(const float4*)(B + (size_t)(cb + lr) * ldb + k0 + lq);
        __syncthreads();
        As[lq + 0][lr] = av.x; As[lq + 1][lr] = av.y;
        As[lq + 2][lr] = av.z; As[lq + 3][lr] = av.w;
        Bs[lq + 0][lr] = bv.x; Bs[lq + 1][lr] = bv.y;
        Bs[lq + 2][lr] = bv.z; Bs[lq + 3][lr] = bv.w;
        __syncthreads();
#pragma unroll
        for (int kk = 0; kk < 16; ++kk) {
            const float4 a4 = *(const float4*)&As[kk][ty << 2];
            const float4 b4 = *(const float4*)&Bs[kk][tx << 2];
            const float ar[4] = {a4.x, a4.y, a4.z, a4.w};
            const float br[4] = {b4.x, b4.y, b4.z, b4.w};
#pragma unroll
            for (int i = 0; i < 4; ++i)
#pragma unroll
                for (int j = 0; j < 4; ++j)
                    acc[i][j] = fmaf(ar[i], br[j], acc[i][j]);
        }
    }
#pragma unroll
    for (int i = 0; i < 4; ++i) {
        const float4 o = make_float4(acc[i][0], acc[i][1], acc[i][2], acc[i][3]);
        *(float4*)(C + (size_t)(rb + (ty << 2) + i) * ldc + cb + (tx << 2)) = o;
    }
}

// ---------------------------------------------------------------------------
// Per-row max of X[row][0..511] (+ optional bias[o]) -> mx[row]
// ---------------------------------------------------------------------------
__global__ __launch_bounds__(256) void row_max_k(
    const float* __restrict__ X, const float* __restrict__ bias,
    float* __restrict__ mx)
{
    const int row = blockIdx.x, t = threadIdx.x;
    const float* x = X + (size_t)row * kH;
    float a = x[t], b = x[t + 256];
    if (bias) { a += bias[t]; b += bias[t + 256]; }
    float m = fmaxf(a, b);
#pragma unroll
    for (int off = 32; off > 0; off >>= 1)
        m = fmaxf(m, __shfl_down(m, off, 64));
    __shared__ float sm[4];
    if ((t & 63) == 0) sm[t >> 6] = m;
    __syncthreads();
    if (t == 0) mx[row] = fmaxf(fmaxf(sm[0], sm[1]), fmaxf(sm[2], sm[3]));
}

// ---------------------------------------------------------------------------
// S1[b,d] = sum_j enc[b,j,d];  S2[b,d] = sum_j enc_part[b,j,d]*enc[b,j,d]
// ---------------------------------------------------------------------------
__global__ __launch_bounds__(256) void s1s2_k(
    const float* __restrict__ enc, const float* __restrict__ enc_part,
    float* __restrict__ S1, float* __restrict__ S2)
{
    const int b = blockIdx.y;
    const int d = blockIdx.x * 256 + threadIdx.x;
    const float* e = enc      + (size_t)b * kTE * kH + d;
    const float* p = enc_part + (size_t)b * kTE * kH + d;
    float s1 = 0.f, s2 = 0.f;
    for (int j = 0; j < kTE; ++j) {
        const float ev = e[(size_t)j * kH];
        const float pv = p[(size_t)j * kH];
        s1 += ev;
        s2 = fmaf(pv, ev, s2);
    }
    S1[b * kH + d] = s1;
    S2[b * kH + d] = s2;
}

// ---------------------------------------------------------------------------
// lse[b,i,j] = mxd[b,i] + mxe[b,j]
//            + log( sum_o exp(dec_part[b,i,o]-mxd) * exp(enc_part[b,j,o]+bias[o]-mxe) )
// One 64(x i) x 64(j) tile per block; exp applied in the staging loader.
// ---------------------------------------------------------------------------
__global__ __launch_bounds__(256) void lse_gemm(
    const float* __restrict__ dec_part, const float* __restrict__ enc_part,
    const float* __restrict__ bias,
    const float* __restrict__ mxd, const float* __restrict__ mxe,
    float* __restrict__ lse)
{
    __shared__ __align__(16) float As[16][68];
    __shared__ __align__(16) float Bs[16][68];
    const int t  = threadIdx.x;
    const int tx = t & 15, ty = t >> 4;
    const int b  = blockIdx.y;
    const int cb = blockIdx.x * 64;                      // j-tile
    const float* A  = dec_part + (size_t)b * kTD * kH;   // 64 x 512
    const float* Bp = enc_part + (size_t)b * kTE * kH;   // 512 x 512
    const int lr = t >> 2;
    const int lq = (t & 3) << 2;
    const float mda = mxd[b * kTD + lr];
    const float mea = mxe[b * kTE + cb + lr];
    float acc[4][4] = {};

    for (int k0 = 0; k0 < kH; k0 += 16) {
        float4 av = *(const float4*)(A + (size_t)lr * kH + k0 + lq);
        float4 bv = *(const float4*)(Bp + (size_t)(cb + lr) * kH + k0 + lq);
        const float4 bb = *(const float4*)(bias + k0 + lq);
        av.x = __expf(av.x - mda); av.y = __expf(av.y - mda);
        av.z = __expf(av.z - mda); av.w = __expf(av.w - mda);
        bv.x = __expf(bv.x + bb.x - mea); bv.y = __expf(bv.y + bb.y - mea);
        bv.z = __expf(bv.z + bb.z - mea); bv.w = __expf(bv.w + bb.w - mea);
        __syncthreads();
        As[lq + 0][lr] = av.x; As[lq + 1][lr] = av.y;
        As[lq + 2][lr] = av.z; As[lq + 3][lr] = av.w;
        Bs[lq + 0][lr] = bv.x; Bs[lq + 1][lr] = bv.y;
        Bs[lq + 2][lr] = bv.z; Bs[lq + 3][lr] = bv.w;
        __syncthreads();
#pragma unroll
        for (int kk = 0; kk < 16; ++kk) {
            const float4 a4 = *(const float4*)&As[kk][ty << 2];
            const float4 b4 = *(const float4*)&Bs[kk][tx << 2];
            const float ar[4] = {a4.x, a4.y, a4.z, a4.w};
            const float br[4] = {b4.x, b4.y, b4.z, b4.w};
#pragma unroll
            for (int i = 0; i < 4; ++i)
#pragma unroll
                for (int j = 0; j < 4; ++j)
                    acc[i][j] = fmaf(ar[i], br[j], acc[i][j]);
        }
    }
    const float me0 = mxe[b * kTE + cb + (tx << 2) + 0];
    const float me1 = mxe[b * kTE + cb + (tx << 2) + 1];
    const float me2 = mxe[b * kTE + cb + (tx << 2) + 2];
    const float me3 = mxe[b * kTE + cb + (tx << 2) + 3];
#pragma unroll
    for (int i = 0; i < 4; ++i) {
        const int r = (ty << 2) + i;
        const float md = mxd[b * kTD + r];
        const float4 o = make_float4(md + me0 + __logf(acc[i][0]),
                                     md + me1 + __logf(acc[i][1]),
                                     md + me2 + __logf(acc[i][2]),
                                     md + me3 + __logf(acc[i][3]));
        *(float4*)(lse + (size_t)b * kTD * kTE + (size_t)r * kTE + cb + (tx << 2)) = o;
    }
}

// ---------------------------------------------------------------------------
// M[b,i,d] = sum_j lse[b,i,j] * enc[b,j,d]   (NN gemm, K = j = 512)
// out[b,i,d] = (dec_part[b,i,d]+bias[d])*S1[b,d] + S2[b,d] - M[b,i,d]
// ---------------------------------------------------------------------------
__global__ __launch_bounds__(256) void final_gemm(
    const float* __restrict__ lse, const float* __restrict__ enc,
    const float* __restrict__ dec_part, const float* __restrict__ bias,
    const float* __restrict__ S1, const float* __restrict__ S2,
    float* __restrict__ out)
{
    __shared__ __align__(16) float As[16][68];
    __shared__ __align__(16) float Bs[16][68];
    const int t  = threadIdx.x;
    const int tx = t & 15, ty = t >> 4;
    const int b  = blockIdx.y;
    const int cb = blockIdx.x * 64;                      // d-tile
    const float* A  = lse + (size_t)b * kTD * kTE;       // 64 x 512 (k = j)
    const float* Bp = enc + (size_t)b * kTE * kH;        // 512 x 512 (row j, col d)
    const int lr = t >> 2,  lq = (t & 3) << 2;           // A loader
    const int bk = t >> 4,  bq = (t & 15) << 2;          // B loader
    float acc[4][4] = {};

    for (int k0 = 0; k0 < kTE; k0 += 16) {
        const float4 av = *(const float4*)(A + (size_t)lr * kTE + k0 + lq);
        const float4 bv = *(const float4*)(Bp + (size_t)(k0 + bk) * kH + cb + bq);
        __syncthreads();
        As[lq + 0][lr] = av.x; As[lq + 1][lr] = av.y;
        As[lq + 2][lr] = av.z; As[lq + 3][lr] = av.w;
        *(float4*)&Bs[bk][bq] = bv;
        __syncthreads();
#pragma unroll
        for (int kk = 0; kk < 16; ++kk) {
            const float4 a4 = *(const float4*)&As[kk][ty << 2];
            const float4 b4 = *(const float4*)&Bs[kk][tx << 2];
            const float ar[4] = {a4.x, a4.y, a4.z, a4.w};
            const float br[4] = {b4.x, b4.y, b4.z, b4.w};
#pragma unroll
            for (int i = 0; i < 4; ++i)
#pragma unroll
                for (int j = 0; j < 4; ++j)
                    acc[i][j] = fmaf(ar[i], br[j], acc[i][j]);
        }
    }
#pragma unroll
    for (int i = 0; i < 4; ++i) {
        const int r  = (ty << 2) + i;
        const int d0 = cb + (tx << 2);
        const float4 dp = *(const float4*)(dec_part + (size_t)(b * kTD + r) * kH + d0);
        const float4 bi = *(const float4*)(bias + d0);
        const float4 s1 = *(const float4*)(S1 + b * kH + d0);
        const float4 s2 = *(const float4*)(S2 + b * kH + d0);
        const float4 o = make_float4(
            fmaf(dp.x + bi.x, s1.x, s2.x) - acc[i][0],
            fmaf(dp.y + bi.y, s1.y, s2.y) - acc[i][1],
            fmaf(dp.z + bi.z, s1.z, s2.z) - acc[i][2],
            fmaf(dp.w + bi.w, s1.w, s2.w) - acc[i][3]);
        *(float4*)(out + (size_t)(b * kTD + r) * kH + d0) = o;
    }
}

// ---------------------------------------------------------------------------
extern "C" void kernel_launch(void* const* d_in, const int* in_sizes, int n_in,
                              void* d_out, int out_size, void* d_ws, size_t ws_size,
                              hipStream_t stream)
{
    (void)in_sizes; (void)n_in; (void)out_size; (void)ws_size;
    const float* enc  = (const float*)d_in[0];   // (8,512,512)
    const float* dec  = (const float*)d_in[1];   // (8,64,512)
    const float* W    = (const float*)d_in[2];   // (512,1024)
    const float* bias = (const float*)d_in[3];   // (512,)
    float* out = (float*)d_out;

    float* ws       = (float*)d_ws;
    float* dec_part = ws;                        // 512*512
    float* enc_part = dec_part + (size_t)kRD * kH;   // 4096*512
    float* mxd      = enc_part + (size_t)kRE * kH;   // 512
    float* mxe      = mxd + kRD;                     // 4096
    float* lse      = mxe + kRE;                     // 8*64*512
    float* S1       = lse + (size_t)kRD * kTE;       // 8*512
    float* S2       = S1 + kB * kH;                  // 8*512

    // dec_part[r,o] = dec[r,:] . W[o, 0:512]
    gemm_nt<<<dim3(kH / 64, kRD / 64), 256, 0, stream>>>(dec, kH, W, 2 * kH,
                                                         dec_part, kH, kH);
    // enc_part[r,o] = enc[r,:] . W[o, 512:1024]
    gemm_nt<<<dim3(kH / 64, kRE / 64), 256, 0, stream>>>(enc, kH, W + kH, 2 * kH,
                                                         enc_part, kH, kH);
    row_max_k<<<kRD, 256, 0, stream>>>(dec_part, nullptr, mxd);
    row_max_k<<<kRE, 256, 0, stream>>>(enc_part, bias, mxe);
    s1s2_k<<<dim3(kH / 256, kB), 256, 0, stream>>>(enc, enc_part, S1, S2);
    lse_gemm<<<dim3(kTE / 64, kB), 256, 0, stream>>>(dec_part, enc_part, bias,
                                                     mxd, mxe, lse);
    final_gemm<<<dim3(kH / 64, kB), 256, 0, stream>>>(lse, enc, dec_part, bias,
                                                      S1, S2, out);
}

// Round 2
// 108.007 us; speedup vs baseline: 1.8942x; 1.8942x over previous
//
#include <hip/hip_runtime.h>

// B=8, T_dec=64, T_enc=512, H=512.  All-bf16-MFMA pipeline:
//   cast_misc:  W -> Wd/We bf16, dec -> bf16, zero S1/S2
//   cast_enc:   enc -> bf16 (straight)
//   gemm1:      part[4608x512] = [dec;enc] @ {Wd|We}^T   (bf16 MFMA, fp32 acc)
//               epilogue: part_bf = bf16(part); uv = bf16(exp(part (+bias)))
//   transpose:  encT[b,d,j] = bf16(enc[b,j,d])   (reuses enc_bf buffer)
//   s1s2:       S1[b,d]=sum_j enc; S2[b,d]=sum_j part*enc   (atomics)
//   pgemm_lse:  lse[b,i,j] = log( U[b,i,:] . V[b,j,:] )     (bf16 MFMA)
//   final:      out = (dec_part+bias)*S1 + S2 - lse @ encT  (bf16 MFMA)
// No max-subtraction: |logit| <= ~14 -> exp well within fp32/bf16 range.

namespace {
constexpr int kH  = 512;
constexpr int kTD = 64;
constexpr int kTE = 512;
constexpr int kB  = 8;
constexpr int kRD = kB * kTD;          // 512
constexpr int kRE = kB * kTE;          // 4096
constexpr int kRT = kRD + kRE;         // 4608 total part rows
}

typedef __attribute__((ext_vector_type(8))) short short8;   // 8 x bf16
typedef __attribute__((ext_vector_type(4))) float floatx4;  // MFMA C/D

__device__ __forceinline__ unsigned short f2bf(float x) {
    unsigned u = __float_as_uint(x);
    u += 0x7fffu + ((u >> 16) & 1u);          // RNE
    return (unsigned short)(u >> 16);
}
__device__ __forceinline__ float bf2f(unsigned short h) {
    return __uint_as_float(((unsigned)h) << 16);
}

// ---------------------------------------------------------------------------
// W(512x1024 fp32) -> Wd,We (512x512 bf16, K-contig); dec -> bf16; zero S1/S2
// grid 2048 x 256  (exactly 524288 threads)
// ---------------------------------------------------------------------------
__global__ __launch_bounds__(256) void cast_misc(
    const float* __restrict__ W, const float* __restrict__ dec,
    unsigned short* __restrict__ Wd, unsigned short* __restrict__ We,
    unsigned short* __restrict__ dec_bf,
    float* __restrict__ S1, float* __restrict__ S2)
{
    const int idx = blockIdx.x * 256 + threadIdx.x;
    const int row = idx >> 10, col = idx & 1023;
    const unsigned short v = f2bf(W[idx]);
    if (col < kH) Wd[row * kH + col] = v;
    else          We[row * kH + (col - kH)] = v;
    if (idx < kRD * kH) dec_bf[idx] = f2bf(dec[idx]);
    if (idx < kB * kH) { S1[idx] = 0.f; S2[idx] = 0.f; }
}

// enc (2M fp32) -> bf16, 4 elements/thread.  grid 2048 x 256
__global__ __launch_bounds__(256) void cast_enc(
    const float* __restrict__ enc, unsigned short* __restrict__ enc_bf)
{
    const int idx = blockIdx.x * 256 + threadIdx.x;
    const float4 v = ((const float4*)enc)[idx];
    ushort4 o;
    o.x = f2bf(v.x); o.y = f2bf(v.y); o.z = f2bf(v.z); o.w = f2bf(v.w);
    ((ushort4*)enc_bf)[idx] = o;
}

// ---------------------------------------------------------------------------
// GEMM-1: one wave per 64x64 tile.  M = 4608 (dec rows 0..511, enc 512..4607),
// N = 512, K = 512.  grid 576 x 64.
// ---------------------------------------------------------------------------
__global__ __launch_bounds__(64) void gemm1(
    const unsigned short* __restrict__ enc_bf,
    const unsigned short* __restrict__ dec_bf,
    const unsigned short* __restrict__ Wd,
    const unsigned short* __restrict__ We,
    const float* __restrict__ bias,
    unsigned short* __restrict__ part_bf, unsigned short* __restrict__ uv)
{
    const int tile = blockIdx.x;
    const int ns = tile & 7, ms = tile >> 3;
    const int l = threadIdx.x;
    const int lr = l & 15, lq = l >> 4;
    const bool isenc = (ms >= 8);
    const unsigned short* A = isenc ? (enc_bf + (size_t)(ms - 8) * 64 * kH)
                                    : (dec_bf + (size_t)ms * 64 * kH);
    const unsigned short* Bw = isenc ? We : Wd;
    const unsigned short* a0 = A + (size_t)lr * kH + lq * 8;
    const unsigned short* b0 = Bw + (size_t)(ns * 64 + lr) * kH + lq * 8;

    floatx4 acc[4][4];
#pragma unroll
    for (int m = 0; m < 4; ++m)
#pragma unroll
        for (int n = 0; n < 4; ++n) acc[m][n] = (floatx4){0.f, 0.f, 0.f, 0.f};

    for (int k0 = 0; k0 < kH; k0 += 32) {
        short8 af[4], bf[4];
#pragma unroll
        for (int m = 0; m < 4; ++m) af[m] = *(const short8*)(a0 + (size_t)m * 16 * kH + k0);
#pragma unroll
        for (int n = 0; n < 4; ++n) bf[n] = *(const short8*)(b0 + (size_t)n * 16 * kH + k0);
#pragma unroll
        for (int m = 0; m < 4; ++m)
#pragma unroll
            for (int n = 0; n < 4; ++n)
                acc[m][n] = __builtin_amdgcn_mfma_f32_16x16x32_bf16(af[m], bf[n], acc[m][n], 0, 0, 0);
    }

    const int rowbase = ms * 64, colbase = ns * 64;
#pragma unroll
    for (int n = 0; n < 4; ++n) {
        const int col = colbase + n * 16 + lr;
        const float bv = isenc ? bias[col] : 0.f;
#pragma unroll
        for (int m = 0; m < 4; ++m) {
            const int row0 = rowbase + m * 16 + lq * 4;
#pragma unroll
            for (int r = 0; r < 4; ++r) {
                const float v = acc[m][n][r];
                const size_t off = (size_t)(row0 + r) * kH + col;
                part_bf[off] = f2bf(v);
                uv[off]      = f2bf(__expf(v + bv));
            }
        }
    }
}

// ---------------------------------------------------------------------------
// encT[b,d,j] = bf16(enc[b,j,d]).  32x32 LDS tiles.  grid (16,16,8) x 256
// ---------------------------------------------------------------------------
__global__ __launch_bounds__(256) void transpose_enc(
    const float* __restrict__ enc, unsigned short* __restrict__ encT)
{
    __shared__ unsigned short s[32][33];
    const int b = blockIdx.z, j0 = blockIdx.y * 32, d0 = blockIdx.x * 32;
    const int tx = threadIdx.x & 31, ty = threadIdx.x >> 5;   // ty: 0..7
    const float* src = enc + ((size_t)b * kTE + j0) * kH + d0;
#pragma unroll
    for (int jj = 0; jj < 32; jj += 8)
        s[ty + jj][tx] = f2bf(src[(size_t)(ty + jj) * kH + tx]);
    __syncthreads();
    unsigned short* dst = encT + ((size_t)b * kH + d0) * kTE + j0;
#pragma unroll
    for (int dd = 0; dd < 32; dd += 8)
        dst[(size_t)(ty + dd) * kTE + tx] = s[tx][ty + dd];
}

// ---------------------------------------------------------------------------
// S1[b,d] += sum_j enc[b,j,d]; S2[b,d] += sum_j part[b,j,d]*enc[b,j,d]
// grid (2, 8, 16) x 256; 32 j per block; atomics (16 contenders/address)
// ---------------------------------------------------------------------------
__global__ __launch_bounds__(256) void s1s2_k(
    const float* __restrict__ enc, const unsigned short* __restrict__ part_bf,
    float* __restrict__ S1, float* __restrict__ S2)
{
    const int d = blockIdx.x * 256 + threadIdx.x;
    const int b = blockIdx.y, jc = blockIdx.z;
    const float* e = enc + ((size_t)b * kTE + jc * 32) * kH + d;
    const unsigned short* p = part_bf + (size_t)(kRD + b * kTE + jc * 32) * kH + d;
    float s1 = 0.f, s2 = 0.f;
#pragma unroll 4
    for (int j = 0; j < 32; ++j) {
        const float ev = e[(size_t)j * kH];
        const float pv = bf2f(p[(size_t)j * kH]);
        s1 += ev;
        s2 = fmaf(pv, ev, s2);
    }
    atomicAdd(&S1[b * kH + d], s1);
    atomicAdd(&S2[b * kH + d], s2);
}

// ---------------------------------------------------------------------------
// lse[b,i,j] = log( U[b,i,:] . V[b,j,:] ), one wave per 16x16 tile.
// grid 1024 x 64.  U rows = uv[b*64 + i], V rows = uv[512 + b*512 + j].
// ---------------------------------------------------------------------------
__global__ __launch_bounds__(64) void pgemm_lse(
    const unsigned short* __restrict__ uv, unsigned short* __restrict__ lse_bf)
{
    const int w = blockIdx.x;
    const int b = w >> 7, rem = w & 127;
    const int it = rem >> 5, jt = rem & 31;
    const int l = threadIdx.x;
    const int lr = l & 15, lq = l >> 4;
    const unsigned short* ua = uv + (size_t)(b * 64 + it * 16 + lr) * kH + lq * 8;
    const unsigned short* vb = uv + (size_t)(kRD + b * kTE + jt * 16 + lr) * kH + lq * 8;

    floatx4 acc = (floatx4){0.f, 0.f, 0.f, 0.f};
    for (int k0 = 0; k0 < kH; k0 += 32)
        acc = __builtin_amdgcn_mfma_f32_16x16x32_bf16(
            *(const short8*)(ua + k0), *(const short8*)(vb + k0), acc, 0, 0, 0);

    const int jcol = jt * 16 + lr;
#pragma unroll
    for (int r = 0; r < 4; ++r) {
        const int i = it * 16 + lq * 4 + r;
        lse_bf[(size_t)(b * kTD + i) * kTE + jcol] = f2bf(__logf(acc[r]));
    }
}

// ---------------------------------------------------------------------------
// out[b,i,d] = (dec_part+bias)*S1 + S2 - sum_j lse[b,i,j]*encT[b,d,j]
// one wave per 16x16 tile.  grid 1024 x 64.
// ---------------------------------------------------------------------------
__global__ __launch_bounds__(64) void final_k(
    const unsigned short* __restrict__ lse_bf,
    const unsigned short* __restrict__ encT,
    const unsigned short* __restrict__ part_bf,
    const float* __restrict__ bias,
    const float* __restrict__ S1, const float* __restrict__ S2,
    float* __restrict__ out)
{
    const int w = blockIdx.x;
    const int b = w >> 7, rem = w & 127;
    const int it = rem >> 5, dt = rem & 31;
    const int l = threadIdx.x;
    const int lr = l & 15, lq = l >> 4;
    const unsigned short* la = lse_bf + (size_t)(b * kTD + it * 16 + lr) * kTE + lq * 8;
    const unsigned short* eb = encT + ((size_t)b * kH + dt * 16 + lr) * kTE + lq * 8;

    floatx4 acc = (floatx4){0.f, 0.f, 0.f, 0.f};
    for (int k0 = 0; k0 < kTE; k0 += 32)
        acc = __builtin_amdgcn_mfma_f32_16x16x32_bf16(
            *(const short8*)(la + k0), *(const short8*)(eb + k0), acc, 0, 0, 0);

    const int d = dt * 16 + lr;
    const float s1 = S1[b * kH + d], s2 = S2[b * kH + d], bv = bias[d];
#pragma unroll
    for (int r = 0; r < 4; ++r) {
        const int i = it * 16 + lq * 4 + r;
        const float dp = bf2f(part_bf[(size_t)(b * kTD + i) * kH + d]);
        out[(size_t)(b * kTD + i) * kH + d] = fmaf(dp + bv, s1, s2) - acc[r];
    }
}

// ---------------------------------------------------------------------------
extern "C" void kernel_launch(void* const* d_in, const int* in_sizes, int n_in,
                              void* d_out, int out_size, void* d_ws, size_t ws_size,
                              hipStream_t stream)
{
    (void)in_sizes; (void)n_in; (void)out_size; (void)ws_size;
    const float* enc  = (const float*)d_in[0];
    const float* dec  = (const float*)d_in[1];
    const float* W    = (const float*)d_in[2];
    const float* bias = (const float*)d_in[3];
    float* out = (float*)d_out;

    char* base = (char*)d_ws;
    unsigned short* part_bf = (unsigned short*)(base);              // 4608*512*2 = 4,718,592
    unsigned short* uv      = (unsigned short*)(base + 4718592);    // 4,718,592
    unsigned short* encX    = (unsigned short*)(base + 9437184);    // 4,194,304 (enc_bf, then encT)
    unsigned short* dec_bf  = (unsigned short*)(base + 13631488);   //   524,288
    unsigned short* Wd      = (unsigned short*)(base + 14155776);   //   524,288
    unsigned short* We      = (unsigned short*)(base + 14680064);   //   524,288
    unsigned short* lse_bf  = (unsigned short*)(base + 15204352);   //   524,288
    float*          S1      = (float*)(base + 15728640);            //    16,384
    float*          S2      = (float*)(base + 15745024);            //    16,384  (total ~15.0 MB)

    cast_misc<<<2048, 256, 0, stream>>>(W, dec, Wd, We, dec_bf, S1, S2);
    cast_enc<<<2048, 256, 0, stream>>>(enc, encX);
    gemm1<<<576, 64, 0, stream>>>(encX, dec_bf, Wd, We, bias, part_bf, uv);
    transpose_enc<<<dim3(16, 16, 8), 256, 0, stream>>>(enc, encX);   // encX now = encT
    s1s2_k<<<dim3(2, 8, 16), 256, 0, stream>>>(enc, part_bf, S1, S2);
    pgemm_lse<<<1024, 64, 0, stream>>>(uv, lse_bf);
    final_k<<<1024, 64, 0, stream>>>(lse_bf, encX, part_bf, bias, S1, S2, out);
}

// Round 3
// 102.676 us; speedup vs baseline: 1.9925x; 1.0519x over previous
//
#include <hip/hip_runtime.h>

// B=8, T_dec=64, T_enc=512, H=512.  bf16-MFMA pipeline, 4 launches:
//   K1 fused_cast: W->Wd/We bf16, dec->bf16, zero S1/S2, enc->enc_bf AND encT
//   K2 gemm1:      part[4608x512] = [dec;enc] @ {Wd|We}^T, 4 waves/block
//                  epilogue: part_bf = bf16(part), uv = bf16(exp(part(+bias)))
//   K3 lse+s1s2:   blocks[0,256): lse[b,i,j] = log(U.V^T)  (split-K x4 + LDS red)
//                  blocks[256,512): S1=sum_j enc, S2=sum_j part*enc (atomics)
//   K4 final:      out = (dec_part+bias)*S1 + S2 - lse @ encT (split-K x4)
// No max-subtraction (|logit|<=~14, exp safe in fp32). absmax ~4 < 14.8 thr.

namespace {
constexpr int kH  = 512;
constexpr int kTD = 64;
constexpr int kTE = 512;
constexpr int kB  = 8;
constexpr int kRD = kB * kTD;          // 512
constexpr int kRE = kB * kTE;          // 4096
}

typedef __attribute__((ext_vector_type(8))) short short8;   // 8 x bf16
typedef __attribute__((ext_vector_type(4))) float floatx4;  // MFMA C/D

__device__ __forceinline__ unsigned short f2bf(float x) {
    unsigned u = __float_as_uint(x);
    u += 0x7fffu + ((u >> 16) & 1u);          // RNE
    return (unsigned short)(u >> 16);
}
__device__ __forceinline__ float bf2f(unsigned short h) {
    return __uint_as_float(((unsigned)h) << 16);
}

// ---------------------------------------------------------------------------
// K1: blocks [0,2048): W cast -> Wd/We, dec cast, zero S1/S2
//     blocks [2048,4096): enc -> enc_bf (straight) + encT (32x32 LDS transpose)
// ---------------------------------------------------------------------------
__global__ __launch_bounds__(256) void fused_cast(
    const float* __restrict__ W, const float* __restrict__ dec,
    const float* __restrict__ enc,
    unsigned short* __restrict__ Wd, unsigned short* __restrict__ We,
    unsigned short* __restrict__ dec_bf,
    unsigned short* __restrict__ enc_bf, unsigned short* __restrict__ encT,
    float* __restrict__ S1, float* __restrict__ S2)
{
    const int blk = blockIdx.x, t = threadIdx.x;
    if (blk < 2048) {
        const int idx = blk * 256 + t;
        const int row = idx >> 10, col = idx & 1023;
        const unsigned short v = f2bf(W[idx]);
        if (col < kH) Wd[row * kH + col] = v;
        else          We[row * kH + (col - kH)] = v;
        if (idx < kRD * kH) dec_bf[idx] = f2bf(dec[idx]);
        if (idx < kB * kH) { S1[idx] = 0.f; S2[idx] = 0.f; }
    } else {
        __shared__ unsigned short s[32][33];
        const int tid = blk - 2048;                    // 0..2047
        const int b = tid >> 8, rem = tid & 255;
        const int j0 = (rem >> 4) * 32, d0 = (rem & 15) * 32;
        const int tx = t & 31, ty = t >> 5;            // ty: 0..7
        const float* src = enc + ((size_t)b * kTE + j0) * kH + d0;
        unsigned short* edst = enc_bf + ((size_t)b * kTE + j0) * kH + d0;
#pragma unroll
        for (int jj = 0; jj < 32; jj += 8) {
            const unsigned short h = f2bf(src[(size_t)(ty + jj) * kH + tx]);
            s[ty + jj][tx] = h;
            edst[(size_t)(ty + jj) * kH + tx] = h;
        }
        __syncthreads();
        unsigned short* tdst = encT + ((size_t)b * kH + d0) * kTE + j0;
#pragma unroll
        for (int dd = 0; dd < 32; dd += 8)
            tdst[(size_t)(ty + dd) * kTE + tx] = s[tx][ty + dd];
    }
}

// ---------------------------------------------------------------------------
// K2: gemm1.  576 blocks x 256 thr; block = 64x64 tile; wave = 32x32 quadrant
// (4 independent MFMA chains).  M=4608 (rows 0..511 dec, 512.. enc), N=512.
// ---------------------------------------------------------------------------
__global__ __launch_bounds__(256) void gemm1(
    const unsigned short* __restrict__ enc_bf,
    const unsigned short* __restrict__ dec_bf,
    const unsigned short* __restrict__ Wd,
    const unsigned short* __restrict__ We,
    const float* __restrict__ bias,
    unsigned short* __restrict__ part_bf, unsigned short* __restrict__ uv)
{
    const int tile = blockIdx.x;
    const int ns = tile & 7, ms = tile >> 3;
    const int t = threadIdx.x, w = t >> 6, l = t & 63;
    const int qm = w >> 1, qn = w & 1;
    const int lr = l & 15, lq = l >> 4;
    const bool isenc = (ms >= 8);
    const unsigned short* A = isenc ? (enc_bf + (size_t)(ms - 8) * 64 * kH)
                                    : (dec_bf + (size_t)ms * 64 * kH);
    const unsigned short* Bw = isenc ? We : Wd;
    const unsigned short* a0 = A + (size_t)(qm * 32 + lr) * kH + lq * 8;
    const unsigned short* b0 = Bw + (size_t)(ns * 64 + qn * 32 + lr) * kH + lq * 8;

    floatx4 acc[2][2];
#pragma unroll
    for (int m = 0; m < 2; ++m)
#pragma unroll
        for (int n = 0; n < 2; ++n) acc[m][n] = (floatx4){0.f, 0.f, 0.f, 0.f};

    for (int k0 = 0; k0 < kH; k0 += 32) {
        short8 af[2], bf[2];
#pragma unroll
        for (int m = 0; m < 2; ++m) af[m] = *(const short8*)(a0 + (size_t)m * 16 * kH + k0);
#pragma unroll
        for (int n = 0; n < 2; ++n) bf[n] = *(const short8*)(b0 + (size_t)n * 16 * kH + k0);
#pragma unroll
        for (int m = 0; m < 2; ++m)
#pragma unroll
            for (int n = 0; n < 2; ++n)
                acc[m][n] = __builtin_amdgcn_mfma_f32_16x16x32_bf16(af[m], bf[n], acc[m][n], 0, 0, 0);
    }

    const int rowbase = ms * 64 + qm * 32, colbase = ns * 64 + qn * 32;
#pragma unroll
    for (int n = 0; n < 2; ++n) {
        const int col = colbase + n * 16 + lr;
        const float bv = isenc ? bias[col] : 0.f;
#pragma unroll
        for (int m = 0; m < 2; ++m) {
            const int row0 = rowbase + m * 16 + lq * 4;
#pragma unroll
            for (int r = 0; r < 4; ++r) {
                const float v = acc[m][n][r];
                const size_t off = (size_t)(row0 + r) * kH + col;
                part_bf[off] = f2bf(v);
                uv[off]      = f2bf(__expf(v + bv));
            }
        }
    }
}

// ---------------------------------------------------------------------------
// K3: blocks [0,256): lse tile 16(i) x 64(j), 4 waves split K=512 4-ways,
//     LDS reduce, log epilogue.   blocks [256,512): s1s2 (32 j per block).
// ---------------------------------------------------------------------------
__global__ __launch_bounds__(256) void lse_s1s2(
    const unsigned short* __restrict__ uv, unsigned short* __restrict__ lse_bf,
    const float* __restrict__ enc, const unsigned short* __restrict__ part_bf,
    float* __restrict__ S1, float* __restrict__ S2)
{
    __shared__ float red[4][16][68];
    const int blk = blockIdx.x, t = threadIdx.x;
    if (blk < 256) {
        const int b = blk >> 5, rem = blk & 31;
        const int it = rem >> 3, jt = rem & 7;
        const int w = t >> 6, l = t & 63;
        const int lr = l & 15, lq = l >> 4;
        const unsigned short* ua = uv + (size_t)(b * 64 + it * 16 + lr) * kH + w * 128 + lq * 8;
        const unsigned short* vb = uv + (size_t)(kRD + b * kTE + jt * 64 + lr) * kH + w * 128 + lq * 8;

        floatx4 acc[4];
#pragma unroll
        for (int n = 0; n < 4; ++n) acc[n] = (floatx4){0.f, 0.f, 0.f, 0.f};
#pragma unroll
        for (int k0 = 0; k0 < 128; k0 += 32) {
            const short8 af = *(const short8*)(ua + k0);
#pragma unroll
            for (int n = 0; n < 4; ++n)
                acc[n] = __builtin_amdgcn_mfma_f32_16x16x32_bf16(
                    af, *(const short8*)(vb + (size_t)n * 16 * kH + k0), acc[n], 0, 0, 0);
        }
#pragma unroll
        for (int n = 0; n < 4; ++n)
#pragma unroll
            for (int r = 0; r < 4; ++r)
                red[w][lq * 4 + r][n * 16 + lr] = acc[n][r];
        __syncthreads();
        const int i = t >> 4, j0 = (t & 15) * 4;
        float4 s = *(const float4*)&red[0][i][j0];
        const float4 s1 = *(const float4*)&red[1][i][j0];
        const float4 s2 = *(const float4*)&red[2][i][j0];
        const float4 s3 = *(const float4*)&red[3][i][j0];
        s.x += s1.x + s2.x + s3.x; s.y += s1.y + s2.y + s3.y;
        s.z += s1.z + s2.z + s3.z; s.w += s1.w + s2.w + s3.w;
        ushort4 o;
        o.x = f2bf(__logf(s.x)); o.y = f2bf(__logf(s.y));
        o.z = f2bf(__logf(s.z)); o.w = f2bf(__logf(s.w));
        *(ushort4*)(lse_bf + (size_t)(b * kTD + it * 16 + i) * kTE + jt * 64 + j0) = o;
    } else {
        const int blk2 = blk - 256;
        const int jc = blk2 & 15, b = (blk2 >> 4) & 7, dh = blk2 >> 7;
        const int d = dh * 256 + t;
        const float* e = enc + ((size_t)b * kTE + jc * 32) * kH + d;
        const unsigned short* p = part_bf + (size_t)(kRD + b * kTE + jc * 32) * kH + d;
        float s1 = 0.f, s2 = 0.f;
#pragma unroll 4
        for (int j = 0; j < 32; ++j) {
            const float ev = e[(size_t)j * kH];
            const float pv = bf2f(p[(size_t)j * kH]);
            s1 += ev;
            s2 = fmaf(pv, ev, s2);
        }
        atomicAdd(&S1[b * kH + d], s1);
        atomicAdd(&S2[b * kH + d], s2);
    }
}

// ---------------------------------------------------------------------------
// K4: final.  256 blocks; tile 16(i) x 64(d), 4 waves split K(j)=512 4-ways,
// LDS reduce, combine epilogue:
// out[b,i,d] = (dec_part+bias)*S1 + S2 - sum_j lse[b,i,j]*encT[b,d,j]
// ---------------------------------------------------------------------------
__global__ __launch_bounds__(256) void final_k(
    const unsigned short* __restrict__ lse_bf,
    const unsigned short* __restrict__ encT,
    const unsigned short* __restrict__ part_bf,
    const float* __restrict__ bias,
    const float* __restrict__ S1, const float* __restrict__ S2,
    float* __restrict__ out)
{
    __shared__ float red[4][16][68];
    const int blk = blockIdx.x, t = threadIdx.x;
    const int b = blk >> 5, rem = blk & 31;
    const int it = rem >> 3, dt = rem & 7;
    const int w = t >> 6, l = t & 63;
    const int lr = l & 15, lq = l >> 4;
    const unsigned short* la = lse_bf + (size_t)(b * kTD + it * 16 + lr) * kTE + w * 128 + lq * 8;
    const unsigned short* eb = encT + ((size_t)b * kH + dt * 64 + lr) * kTE + w * 128 + lq * 8;

    floatx4 acc[4];
#pragma unroll
    for (int n = 0; n < 4; ++n) acc[n] = (floatx4){0.f, 0.f, 0.f, 0.f};
#pragma unroll
    for (int k0 = 0; k0 < 128; k0 += 32) {
        const short8 af = *(const short8*)(la + k0);
#pragma unroll
        for (int n = 0; n < 4; ++n)
            acc[n] = __builtin_amdgcn_mfma_f32_16x16x32_bf16(
                af, *(const short8*)(eb + (size_t)n * 16 * kTE + k0), acc[n], 0, 0, 0);
    }
#pragma unroll
    for (int n = 0; n < 4; ++n)
#pragma unroll
        for (int r = 0; r < 4; ++r)
            red[w][lq * 4 + r][n * 16 + lr] = acc[n][r];
    __syncthreads();
    const int i = t >> 4, d0 = (t & 15) * 4;
    float4 m = *(const float4*)&red[0][i][d0];
    const float4 m1 = *(const float4*)&red[1][i][d0];
    const float4 m2 = *(const float4*)&red[2][i][d0];
    const float4 m3 = *(const float4*)&red[3][i][d0];
    m.x += m1.x + m2.x + m3.x; m.y += m1.y + m2.y + m3.y;
    m.z += m1.z + m2.z + m3.z; m.w += m1.w + m2.w + m3.w;

    const int gd = dt * 64 + d0;
    const float4 s1 = *(const float4*)(S1 + b * kH + gd);
    const float4 s2 = *(const float4*)(S2 + b * kH + gd);
    const float4 bi = *(const float4*)(bias + gd);
    const int row = b * kTD + it * 16 + i;
    const ushort4 dp = *(const ushort4*)(part_bf + (size_t)row * kH + gd);
    float4 o;
    o.x = fmaf(bf2f(dp.x) + bi.x, s1.x, s2.x) - m.x;
    o.y = fmaf(bf2f(dp.y) + bi.y, s1.y, s2.y) - m.y;
    o.z = fmaf(bf2f(dp.z) + bi.z, s1.z, s2.z) - m.z;
    o.w = fmaf(bf2f(dp.w) + bi.w, s1.w, s2.w) - m.w;
    *(float4*)(out + (size_t)row * kH + gd) = o;
}

// ---------------------------------------------------------------------------
extern "C" void kernel_launch(void* const* d_in, const int* in_sizes, int n_in,
                              void* d_out, int out_size, void* d_ws, size_t ws_size,
                              hipStream_t stream)
{
    (void)in_sizes; (void)n_in; (void)out_size; (void)ws_size;
    const float* enc  = (const float*)d_in[0];
    const float* dec  = (const float*)d_in[1];
    const float* W    = (const float*)d_in[2];
    const float* bias = (const float*)d_in[3];
    float* out = (float*)d_out;

    char* base = (char*)d_ws;
    unsigned short* part_bf = (unsigned short*)(base);              // 4,718,592
    unsigned short* uv      = (unsigned short*)(base + 4718592);    // 4,718,592
    unsigned short* enc_bf  = (unsigned short*)(base + 9437184);    // 4,194,304
    unsigned short* encT    = (unsigned short*)(base + 13631488);   // 4,194,304
    unsigned short* dec_bf  = (unsigned short*)(base + 17825792);   //   524,288
    unsigned short* Wd      = (unsigned short*)(base + 18350080);   //   524,288
    unsigned short* We      = (unsigned short*)(base + 18874368);   //   524,288
    unsigned short* lse_bf  = (unsigned short*)(base + 19398656);   //   524,288
    float*          S1      = (float*)(base + 19922944);            //    16,384
    float*          S2      = (float*)(base + 19939328);            //    16,384

    fused_cast<<<4096, 256, 0, stream>>>(W, dec, enc, Wd, We, dec_bf,
                                         enc_bf, encT, S1, S2);
    gemm1<<<576, 256, 0, stream>>>(enc_bf, dec_bf, Wd, We, bias, part_bf, uv);
    lse_s1s2<<<512, 256, 0, stream>>>(uv, lse_bf, enc, part_bf, S1, S2);
    final_k<<<256, 256, 0, stream>>>(lse_bf, encT, part_bf, bias, S1, S2, out);
}

// Round 4
// 91.256 us; speedup vs baseline: 2.2419x; 1.1251x over previous
//
#include <hip/hip_runtime.h>

// B=8, T_dec=64, T_enc=512, H=512.  bf16-MFMA pipeline, 4 launches, with all
// MFMA operands stored in FRAGMENT-MAJOR layout: each 16-row x 32-k tile holds
// the 64 lanes' short8 fragments contiguously (1 KB), so every GEMM operand
// load is one coalesced dwordx4 per lane (base + lane*16) instead of a
// 16-segment row gather.
//   K1 fused_cast: W->Wd_f/We_f, dec->dec_f, enc->enc_f + encT_f, zero S1/S2
//   K2 gemm1:      part = [dec;enc] @ {Wd|We}^T; epilogue via LDS bounce ->
//                  part_bf (plain, ushort8 stores) + uv_f = exp(part(+bias))
//   K3 lse+s1s2:   lse_f = log(U.V^T) (split-K x4, LDS reduce) ; s1s2 atomics
//   K4 final:      out = (dec_part+bias)*S1 + S2 - lse @ encT
// All K = 512 -> fragTile(rtile, kt) = (rtile*16 + kt)*512 ushorts.

namespace {
constexpr int kH  = 512;
constexpr int kTD = 64;
constexpr int kTE = 512;
constexpr int kB  = 8;
constexpr int kRD = kB * kTD;          // 512
constexpr int kRE = kB * kTE;          // 4096
}

typedef __attribute__((ext_vector_type(8))) short short8;   // 8 x bf16
typedef __attribute__((ext_vector_type(4))) float floatx4;  // MFMA C/D

__device__ __forceinline__ unsigned short f2bf(float x) {
    unsigned u = __float_as_uint(x);
    u += 0x7fffu + ((u >> 16) & 1u);          // RNE
    return (unsigned short)(u >> 16);
}
__device__ __forceinline__ float bf2f(unsigned short h) {
    return __uint_as_float(((unsigned)h) << 16);
}
__device__ __forceinline__ size_t fragTile(int rtile, int kt) {
    return ((size_t)rtile * 16 + kt) * 512;   // ushort index of tile base
}
__device__ __forceinline__ short8 pack8(float4 a, float4 b) {
    short8 r;
    r[0] = (short)f2bf(a.x); r[1] = (short)f2bf(a.y);
    r[2] = (short)f2bf(a.z); r[3] = (short)f2bf(a.w);
    r[4] = (short)f2bf(b.x); r[5] = (short)f2bf(b.y);
    r[6] = (short)f2bf(b.z); r[7] = (short)f2bf(b.w);
    return r;
}

// ---------------------------------------------------------------------------
// K1: blocks [0,256): W -> Wd_f/We_f (frag), blocks [0,32) also zero S12.
//     blocks [256,384): dec -> dec_f (frag)
//     blocks [384,1408): enc -> enc_f (frag) + encT_f (frag, LDS transpose)
// ---------------------------------------------------------------------------
__global__ __launch_bounds__(256) void fused_cast(
    const float* __restrict__ W, const float* __restrict__ dec,
    const float* __restrict__ enc,
    unsigned short* __restrict__ Wd_f, unsigned short* __restrict__ We_f,
    unsigned short* __restrict__ dec_f,
    unsigned short* __restrict__ enc_f, unsigned short* __restrict__ encT_f,
    float* __restrict__ S12)
{
    const int blk = blockIdx.x, t = threadIdx.x;
    const int w = t >> 6, l = t & 63;
    const int lr = l & 15, lc = l >> 4;
    if (blk < 256) {
        const int gw = blk * 4 + w;               // [0,1024)
        const int sel = gw >> 9, rem = gw & 511;
        const int ot = rem >> 4, kt = rem & 15;
        const int o = ot * 16 + lr;
        const float* src = W + (size_t)o * 1024 + sel * 512 + kt * 32 + lc * 8;
        const float4 v0 = *(const float4*)src;
        const float4 v1 = *(const float4*)(src + 4);
        unsigned short* dst = (sel ? We_f : Wd_f) + fragTile(ot, kt) + l * 8;
        *(short8*)dst = pack8(v0, v1);
        if (blk < 32) S12[blk * 256 + t] = 0.f;
    } else if (blk < 384) {
        const int gw = (blk - 256) * 4 + w;       // [0,512)
        const int rt = gw >> 4, kt = gw & 15;
        const int r = rt * 16 + lr;
        const float* src = dec + (size_t)r * kH + kt * 32 + lc * 8;
        const float4 v0 = *(const float4*)src;
        const float4 v1 = *(const float4*)(src + 4);
        *(short8*)(dec_f + fragTile(rt, kt) + l * 8) = pack8(v0, v1);
    } else {
        __shared__ unsigned short s[64][36];      // 64 j x 32 d (+pad)
        const int e = blk - 384;                  // [0,1024)
        const int kt = e & 15, jt = (e >> 4) & 7, b = e >> 7;
        const int j0 = jt * 64, d0 = kt * 32;
        const int jl = w * 16 + lr;               // local j (0..63)
        const float* src = enc + ((size_t)(b * kTE + j0 + jl)) * kH + d0 + lc * 8;
        const float4 v0 = *(const float4*)src;
        const float4 v1 = *(const float4*)(src + 4);
        const short8 p = pack8(v0, v1);
        *(short8*)(enc_f + fragTile(b * 32 + jt * 4 + w, kt) + l * 8) = p;
#pragma unroll
        for (int i = 0; i < 8; ++i) s[jl][lc * 8 + i] = (unsigned short)p[i];
        __syncthreads();
        const int dt = w >> 1, jc = w & 1;        // wave -> one encT frag tile
        const int dl = dt * 16 + lr;              // local d (0..31)
        const int j8 = jc * 32 + lc * 8;          // local j chunk
        short8 v;
#pragma unroll
        for (int i = 0; i < 8; ++i) v[i] = (short)s[j8 + i][dl];
        *(short8*)(encT_f + fragTile(b * 32 + kt * 2 + dt, jt * 2 + jc) + l * 8) = v;
    }
}

// ---------------------------------------------------------------------------
// K2: gemm1.  576 blocks; block = 64x64 tile; wave = 32x32 quadrant.
// M = 4608 (rows 0..511 dec, 512.. enc), N = 512, K = 512.
// Epilogue: acc -> LDS -> part_bf (plain) + uv_f (frag) with exp(+bias).
// ---------------------------------------------------------------------------
__global__ __launch_bounds__(256) void gemm1(
    const unsigned short* __restrict__ enc_f,
    const unsigned short* __restrict__ dec_f,
    const unsigned short* __restrict__ Wd_f,
    const unsigned short* __restrict__ We_f,
    const float* __restrict__ bias,
    unsigned short* __restrict__ part_bf, unsigned short* __restrict__ uv_f)
{
    __shared__ float As[64][68];
    const int tile = blockIdx.x;
    const int ns = tile & 7, ms = tile >> 3;
    const int t = threadIdx.x, w = t >> 6, l = t & 63;
    const int qm = w >> 1, qn = w & 1;
    const bool isenc = (ms >= 8);
    const unsigned short* A = isenc ? enc_f : dec_f;
    const unsigned short* Bw = isenc ? We_f : Wd_f;
    const int art = (isenc ? (ms - 8) : ms) * 4 + qm * 2;
    const int brt = ns * 4 + qn * 2;

    floatx4 acc[2][2];
#pragma unroll
    for (int m = 0; m < 2; ++m)
#pragma unroll
        for (int n = 0; n < 2; ++n) acc[m][n] = (floatx4){0.f, 0.f, 0.f, 0.f};

    for (int kt = 0; kt < 16; ++kt) {
        short8 af[2], bfr[2];
#pragma unroll
        for (int m = 0; m < 2; ++m)
            af[m] = *(const short8*)(A + fragTile(art + m, kt) + l * 8);
#pragma unroll
        for (int n = 0; n < 2; ++n)
            bfr[n] = *(const short8*)(Bw + fragTile(brt + n, kt) + l * 8);
#pragma unroll
        for (int m = 0; m < 2; ++m)
#pragma unroll
            for (int n = 0; n < 2; ++n)
                acc[m][n] = __builtin_amdgcn_mfma_f32_16x16x32_bf16(af[m], bfr[n], acc[m][n], 0, 0, 0);
    }

    const int lr = l & 15, lq = l >> 4;
#pragma unroll
    for (int m = 0; m < 2; ++m)
#pragma unroll
        for (int n = 0; n < 2; ++n)
#pragma unroll
            for (int r = 0; r < 4; ++r)
                As[qm * 32 + m * 16 + lq * 4 + r][qn * 32 + n * 16 + lr] = acc[m][n][r];
    __syncthreads();

    const int rowbase = ms * 64, colbase = ns * 64;
    // part_bf plain: 8 rows x 128 B per wave-store, fully coalesced
#pragma unroll
    for (int h = 0; h < 2; ++h) {
        const int a = h * 256 + t;
        const int row = a >> 3, cc = (a & 7) * 8;
        const float4 v0 = *(const float4*)&As[row][cc];
        const float4 v1 = *(const float4*)&As[row][cc + 4];
        *(short8*)(part_bf + (size_t)(rowbase + row) * kH + colbase + cc) = pack8(v0, v1);
    }
    // uv_f frag: slot s -> (rt, kc, fl); tile uniform per wave per iteration
#pragma unroll
    for (int h = 0; h < 2; ++h) {
        const int s = h * 256 + t;
        const int rt = s >> 7, kc = (s >> 6) & 1, fl = s & 63;
        const int row = rt * 16 + (fl & 15);
        const int col = kc * 32 + (fl >> 4) * 8;
        const float4 v0 = *(const float4*)&As[row][col];
        const float4 v1 = *(const float4*)&As[row][col + 4];
        float4 b0 = make_float4(0.f, 0.f, 0.f, 0.f), b1 = b0;
        if (isenc) {
            b0 = *(const float4*)(bias + colbase + col);
            b1 = *(const float4*)(bias + colbase + col + 4);
        }
        short8 u;
        u[0] = (short)f2bf(__expf(v0.x + b0.x));
        u[1] = (short)f2bf(__expf(v0.y + b0.y));
        u[2] = (short)f2bf(__expf(v0.z + b0.z));
        u[3] = (short)f2bf(__expf(v0.w + b0.w));
        u[4] = (short)f2bf(__expf(v1.x + b1.x));
        u[5] = (short)f2bf(__expf(v1.y + b1.y));
        u[6] = (short)f2bf(__expf(v1.z + b1.z));
        u[7] = (short)f2bf(__expf(v1.w + b1.w));
        *(short8*)(uv_f + fragTile(ms * 4 + rt, ns * 2 + kc) + fl * 8) = u;
    }
}

// ---------------------------------------------------------------------------
// K3: blocks [0,256): lse tile 16(i) x 64(j), 4 waves split K=512 4-ways,
//     LDS reduce, log epilogue -> lse_f (frag layout).
//     blocks [256,512): S1 = sum_j enc, S2 = sum_j part*enc (atomics).
// ---------------------------------------------------------------------------
__global__ __launch_bounds__(256) void lse_s1s2(
    const unsigned short* __restrict__ uv_f, unsigned short* __restrict__ lse_f,
    const float* __restrict__ enc, const unsigned short* __restrict__ part_bf,
    float* __restrict__ S12)
{
    __shared__ float red[4][16][68];
    const int blk = blockIdx.x, t = threadIdx.x;
    if (blk < 256) {
        const int b = blk >> 5, rem = blk & 31;
        const int it = rem >> 3, jt = rem & 7;
        const int w = t >> 6, l = t & 63;
        const int art = b * 4 + it;               // U rows (dec region)
        const int vrt0 = 32 + b * 32 + jt * 4;    // V rows (enc region)

        floatx4 acc[4];
#pragma unroll
        for (int n = 0; n < 4; ++n) acc[n] = (floatx4){0.f, 0.f, 0.f, 0.f};
#pragma unroll
        for (int kk = 0; kk < 4; ++kk) {
            const int kt = w * 4 + kk;
            const short8 af = *(const short8*)(uv_f + fragTile(art, kt) + l * 8);
#pragma unroll
            for (int n = 0; n < 4; ++n)
                acc[n] = __builtin_amdgcn_mfma_f32_16x16x32_bf16(
                    af, *(const short8*)(uv_f + fragTile(vrt0 + n, kt) + l * 8), acc[n], 0, 0, 0);
        }
        const int lr = l & 15, lq = l >> 4;
#pragma unroll
        for (int n = 0; n < 4; ++n)
#pragma unroll
            for (int r = 0; r < 4; ++r)
                red[w][lq * 4 + r][n * 16 + lr] = acc[n][r];
        __syncthreads();
        const int s = t >> 1, h = t & 1;
        const int kc = s >> 6, fl = s & 63;
        const int i = fl & 15;
        const int j = kc * 32 + (fl >> 4) * 8 + h * 4;
        float4 sum = *(const float4*)&red[0][i][j];
        const float4 s1 = *(const float4*)&red[1][i][j];
        const float4 s2 = *(const float4*)&red[2][i][j];
        const float4 s3 = *(const float4*)&red[3][i][j];
        sum.x += s1.x + s2.x + s3.x; sum.y += s1.y + s2.y + s3.y;
        sum.z += s1.z + s2.z + s3.z; sum.w += s1.w + s2.w + s3.w;
        ushort4 o;
        o.x = f2bf(__logf(sum.x)); o.y = f2bf(__logf(sum.y));
        o.z = f2bf(__logf(sum.z)); o.w = f2bf(__logf(sum.w));
        *(ushort4*)(lse_f + fragTile(b * 4 + it, jt * 2 + kc) + fl * 8 + h * 4) = o;
    } else {
        const int blk2 = blk - 256;
        const int jc = blk2 & 15, b = (blk2 >> 4) & 7, dh = blk2 >> 7;
        const int d = dh * 256 + t;
        const float* e = enc + ((size_t)b * kTE + jc * 32) * kH + d;
        const unsigned short* p = part_bf + (size_t)(kRD + b * kTE + jc * 32) * kH + d;
        float s1 = 0.f, s2 = 0.f;
#pragma unroll 4
        for (int j = 0; j < 32; ++j) {
            const float ev = e[(size_t)j * kH];
            const float pv = bf2f(p[(size_t)j * kH]);
            s1 += ev;
            s2 = fmaf(pv, ev, s2);
        }
        atomicAdd(&S12[b * kH + d], s1);
        atomicAdd(&S12[4096 + b * kH + d], s2);
    }
}

// ---------------------------------------------------------------------------
// K4: final.  256 blocks; tile 16(i) x 64(d), 4 waves split K(j)=512 4-ways.
// out[b,i,d] = (dec_part+bias)*S1 + S2 - sum_j lse[b,i,j]*encT[b,d,j]
// ---------------------------------------------------------------------------
__global__ __launch_bounds__(256) void final_k(
    const unsigned short* __restrict__ lse_f,
    const unsigned short* __restrict__ encT_f,
    const unsigned short* __restrict__ part_bf,
    const float* __restrict__ bias,
    const float* __restrict__ S12,
    float* __restrict__ out)
{
    __shared__ float red[4][16][68];
    const int blk = blockIdx.x, t = threadIdx.x;
    const int b = blk >> 5, rem = blk & 31;
    const int it = rem >> 3, dt = rem & 7;
    const int w = t >> 6, l = t & 63;
    const int art = b * 4 + it;                   // lse rows
    const int brt0 = b * 32 + dt * 4;             // encT rows (d)

    floatx4 acc[4];
#pragma unroll
    for (int n = 0; n < 4; ++n) acc[n] = (floatx4){0.f, 0.f, 0.f, 0.f};
#pragma unroll
    for (int kk = 0; kk < 4; ++kk) {
        const int kt = w * 4 + kk;
        const short8 af = *(const short8*)(lse_f + fragTile(art, kt) + l * 8);
#pragma unroll
        for (int n = 0; n < 4; ++n)
            acc[n] = __builtin_amdgcn_mfma_f32_16x16x32_bf16(
                af, *(const short8*)(encT_f + fragTile(brt0 + n, kt) + l * 8), acc[n], 0, 0, 0);
    }
    const int lr = l & 15, lq = l >> 4;
#pragma unroll
    for (int n = 0; n < 4; ++n)
#pragma unroll
        for (int r = 0; r < 4; ++r)
            red[w][lq * 4 + r][n * 16 + lr] = acc[n][r];
    __syncthreads();
    const int i = t >> 4, d0 = (t & 15) * 4;
    float4 m = *(const float4*)&red[0][i][d0];
    const float4 m1 = *(const float4*)&red[1][i][d0];
    const float4 m2 = *(const float4*)&red[2][i][d0];
    const float4 m3 = *(const float4*)&red[3][i][d0];
    m.x += m1.x + m2.x + m3.x; m.y += m1.y + m2.y + m3.y;
    m.z += m1.z + m2.z + m3.z; m.w += m1.w + m2.w + m3.w;

    const int gd = dt * 64 + d0;
    const float4 s1 = *(const float4*)(S12 + b * kH + gd);
    const float4 s2 = *(const float4*)(S12 + 4096 + b * kH + gd);
    const float4 bi = *(const float4*)(bias + gd);
    const int row = b * kTD + it * 16 + i;
    const ushort4 dp = *(const ushort4*)(part_bf + (size_t)row * kH + gd);
    float4 o;
    o.x = fmaf(bf2f(dp.x) + bi.x, s1.x, s2.x) - m.x;
    o.y = fmaf(bf2f(dp.y) + bi.y, s1.y, s2.y) - m.y;
    o.z = fmaf(bf2f(dp.z) + bi.z, s1.z, s2.z) - m.z;
    o.w = fmaf(bf2f(dp.w) + bi.w, s1.w, s2.w) - m.w;
    *(float4*)(out + (size_t)row * kH + gd) = o;
}

// ---------------------------------------------------------------------------
extern "C" void kernel_launch(void* const* d_in, const int* in_sizes, int n_in,
                              void* d_out, int out_size, void* d_ws, size_t ws_size,
                              hipStream_t stream)
{
    (void)in_sizes; (void)n_in; (void)out_size; (void)ws_size;
    const float* enc  = (const float*)d_in[0];
    const float* dec  = (const float*)d_in[1];
    const float* W    = (const float*)d_in[2];
    const float* bias = (const float*)d_in[3];
    float* out = (float*)d_out;

    char* base = (char*)d_ws;
    unsigned short* part_bf = (unsigned short*)(base);              // 4,718,592
    unsigned short* uv_f    = (unsigned short*)(base + 4718592);    // 4,718,592
    unsigned short* enc_f   = (unsigned short*)(base + 9437184);    // 4,194,304
    unsigned short* encT_f  = (unsigned short*)(base + 13631488);   // 4,194,304
    unsigned short* dec_f   = (unsigned short*)(base + 17825792);   //   524,288
    unsigned short* Wd_f    = (unsigned short*)(base + 18350080);   //   524,288
    unsigned short* We_f    = (unsigned short*)(base + 18874368);   //   524,288
    unsigned short* lse_f   = (unsigned short*)(base + 19398656);   //   524,288
    float*          S12     = (float*)(base + 19922944);            //    32,768

    fused_cast<<<1408, 256, 0, stream>>>(W, dec, enc, Wd_f, We_f, dec_f,
                                         enc_f, encT_f, S12);
    gemm1<<<576, 256, 0, stream>>>(enc_f, dec_f, Wd_f, We_f, bias, part_bf, uv_f);
    lse_s1s2<<<512, 256, 0, stream>>>(uv_f, lse_f, enc, part_bf, S12);
    final_k<<<256, 256, 0, stream>>>(lse_f, encT_f, part_bf, bias, S12, out);
}